// Round 1
// baseline (203.232 us; speedup 1.0000x reference)
//
#include <hip/hip_runtime.h>

// CostVolume2D: B=8, H=256, W=512, C=32, n_disp=12, stride=1 (all compile-time).
// cost[b,h,w,d] = sum_c |feat_l[b,h,w,c] - feat_r[b,h,w-d,c]|, feat_r zero-padded left.
// Layout NHWC (C contiguous), output [..., 12] contiguous.

constexpr int Wd   = 512;
constexpr int Cd   = 32;
constexpr int ND   = 12;
constexpr int CQ   = Cd / 4;          // 8 float4 per pixel

__global__ __launch_bounds__(256) void cost_volume_kernel(
    const float* __restrict__ fl,
    const float* __restrict__ fr,
    float* __restrict__ out)
{
    // One thread per output pixel (b,h,w). Total = 8*256*512 = 1,048,576.
    const int idx = blockIdx.x * blockDim.x + threadIdx.x;   // pixel index
    const int w  = idx & (Wd - 1);
    const int bh = idx >> 9;                                  // b*H + h

    // Load feat_l[b,h,w,:] into registers (8 x float4 = 32 VGPRs).
    const float4* lptr = reinterpret_cast<const float4*>(fl + (size_t)idx * Cd);
    float4 L[CQ];
#pragma unroll
    for (int q = 0; q < CQ; ++q) L[q] = lptr[q];

    // |feat_l| sum for the zero-padded (w < d) case — compute once.
    float lsum = 0.f;
#pragma unroll
    for (int q = 0; q < CQ; ++q) {
        lsum += fabsf(L[q].x) + fabsf(L[q].y) + fabsf(L[q].z) + fabsf(L[q].w);
    }

    const float4* rbase = reinterpret_cast<const float4*>(fr + (size_t)bh * Wd * Cd);

    float res[ND];
#pragma unroll
    for (int d = 0; d < ND; ++d) {
        if (w >= d) {
            const float4* rp = rbase + (size_t)(w - d) * CQ;
            float acc = 0.f;
#pragma unroll
            for (int q = 0; q < CQ; ++q) {
                float4 r = rp[q];
                acc += fabsf(L[q].x - r.x) + fabsf(L[q].y - r.y)
                     + fabsf(L[q].z - r.z) + fabsf(L[q].w - r.w);
            }
            res[d] = acc;
        } else {
            res[d] = lsum;   // feat_r shifted out -> zeros
        }
    }

    // Store 12 contiguous floats as 3 float4s.
    float4* op = reinterpret_cast<float4*>(out + (size_t)idx * ND);
    op[0] = make_float4(res[0], res[1], res[2],  res[3]);
    op[1] = make_float4(res[4], res[5], res[6],  res[7]);
    op[2] = make_float4(res[8], res[9], res[10], res[11]);
}

extern "C" void kernel_launch(void* const* d_in, const int* in_sizes, int n_in,
                              void* d_out, int out_size, void* d_ws, size_t ws_size,
                              hipStream_t stream)
{
    const float* fl = (const float*)d_in[0];
    const float* fr = (const float*)d_in[1];
    float* out = (float*)d_out;

    const int n_pixels = 8 * 256 * 512;          // B*H*W
    const int block = 256;
    const int grid  = n_pixels / block;          // 4096 blocks

    cost_volume_kernel<<<grid, block, 0, stream>>>(fl, fr, out);
}

// Round 2
// 73.663 us; speedup vs baseline: 2.7590x; 2.7590x over previous
//
#include <hip/hip_runtime.h>

// CostVolume2D: B=8, H=256, W=512, C=32, n_disp=12, stride=1.
// cost[b,h,w,d] = sum_c |feat_l[b,h,w,c] - feat_r[b,h,w-d,c]|, feat_r zero-padded left.
// NHWC layout, output [...,12] contiguous.
//
// Strategy: block = 256 threads = half a row (256 consecutive w at one b,h).
// Stage feat_r columns [wstart-11 .. wstart+255] into LDS once (global_load_lds,
// 16B, XOR-swizzled via pre-swizzled global source per rule #21), then each
// thread reads its 12 disparity columns from LDS (96 ds_read_b128, conflict-free).

constexpr int Wd = 512;
constexpr int Cd = 32;
constexpr int ND = 12;
constexpr int TILE_W = 256;
constexpr int PAD_COLS = 288;           // 267 needed; padded to a multiple of 8 waves*64 chunks

__global__ __launch_bounds__(256) void cost_volume_kernel(
    const float* __restrict__ fl,
    const float* __restrict__ fr,
    float* __restrict__ out)
{
    __shared__ float lds[PAD_COLS * Cd];   // 36 KiB

    const int tid   = threadIdx.x;
    const int wave  = tid >> 6;
    const int lane  = tid & 63;
    const int wstart = (blockIdx.x & 1) * TILE_W;
    const int bh     = blockIdx.x >> 1;          // b*H + h
    const float* fr_row = fr + (size_t)bh * Wd * Cd;

    // ---- Stage feat_r tile into LDS (swizzled content, linear writes).
    // LDS slot (rel, s) holds global (g(rel), s ^ (rel&7)); 2304 16B chunks total.
    #pragma unroll
    for (int it = 0; it < 9; ++it) {
        const int chunk = (it * 4 + wave) * 64 + lane;   // 0..2303
        const int rel   = chunk >> 3;                    // padded column index
        const int s     = chunk & 7;                     // swizzled quarter slot
        const int gq    = s ^ (rel & 7);                 // source channel-quarter
        int g = wstart - 11 + rel;
        g = min(max(g, 0), Wd - 1);                      // clamp; clamped cols never read
        const float* src = fr_row + g * Cd + gq * 4;
        __builtin_amdgcn_global_load_lds(
            (const __attribute__((address_space(1))) void*)src,
            (__attribute__((address_space(3))) void*)((char*)lds + (size_t)(it * 4 + wave) * 1024),
            16, 0, 0);
    }

    // ---- feat_l[b,h,w,:] into registers (overlaps with staging loads).
    const int w     = wstart + tid;
    const size_t pix = (size_t)bh * Wd + w;
    const float4* lp = reinterpret_cast<const float4*>(fl + pix * Cd);
    float4 L[8];
    #pragma unroll
    for (int q = 0; q < 8; ++q) L[q] = lp[q];

    float lsum = 0.f;
    #pragma unroll
    for (int q = 0; q < 8; ++q)
        lsum += fabsf(L[q].x) + fabsf(L[q].y) + fabsf(L[q].z) + fabsf(L[q].w);

    __syncthreads();   // drains global_load_lds (vmcnt) + makes tile visible

    // ---- 12 disparities from LDS. rel = tid + 11 - d in [0, 266].
    float res[ND];
    #pragma unroll
    for (int d = 0; d < ND; ++d) res[d] = 0.f;

    #pragma unroll
    for (int q = 0; q < 8; ++q) {
        const float4 Lq = L[q];
        #pragma unroll
        for (int d = 0; d < ND; ++d) {
            const int rel = tid + 11 - d;
            const int s   = q ^ (rel & 7);
            const float4 r = *reinterpret_cast<const float4*>(&lds[rel * Cd + s * 4]);
            res[d] += fabsf(Lq.x - r.x) + fabsf(Lq.y - r.y)
                    + fabsf(Lq.z - r.z) + fabsf(Lq.w - r.w);
        }
    }

    // Left edge: w < d -> feat_r shifted out entirely (zeros) -> sum|feat_l|.
    #pragma unroll
    for (int d = 0; d < ND; ++d)
        if (w < d) res[d] = lsum;

    float4* op = reinterpret_cast<float4*>(out + pix * ND);
    op[0] = make_float4(res[0], res[1], res[2],  res[3]);
    op[1] = make_float4(res[4], res[5], res[6],  res[7]);
    op[2] = make_float4(res[8], res[9], res[10], res[11]);
}

extern "C" void kernel_launch(void* const* d_in, const int* in_sizes, int n_in,
                              void* d_out, int out_size, void* d_ws, size_t ws_size,
                              hipStream_t stream)
{
    const float* fl = (const float*)d_in[0];
    const float* fr = (const float*)d_in[1];
    float* out = (float*)d_out;

    const int n_pixels = 8 * 256 * 512;          // B*H*W
    const int block = 256;
    const int grid  = n_pixels / block;          // 4096 blocks

    cost_volume_kernel<<<grid, block, 0, stream>>>(fl, fr, out);
}